// Round 10
// baseline (186.078 us; speedup 1.0000x reference)
//
#include <hip/hip_runtime.h>
#include <cstdint>
#include <cstddef>

#define Bq 4
#define T 2048
#define Dm 768
#define H 8
#define HD 96
#define BH 32
#define QEL ((size_t)BH*T*HD)     // q / v^T element count
#define KEL ((size_t)BH*T*128)    // padded K element count
#define PSTRIDE 98304             // tiled panel stride = (768/8)*128*8 elems
// q pre-scaled by HD^-0.5 * log2(e): attention uses exp2 directly
#define QS 0.14724703336f
#define KVB 64
#define M0 12.0f                  // fixed softmax max (log2 domain)

typedef unsigned int u32;
typedef unsigned long long u64;
typedef _Float16 f16x8 __attribute__((ext_vector_type(8)));
typedef _Float16 f16x4 __attribute__((ext_vector_type(4)));
typedef float f32x4 __attribute__((ext_vector_type(4)));

// ---------------------------------------------------------------------------
// f32 [R][768] row-major -> fp16 tiled [R/128][96][128][8].
// ---------------------------------------------------------------------------
__global__ __launch_bounds__(256)
void cvt_tile(const float* __restrict__ in, _Float16* __restrict__ out)
{
    const int tid  = threadIdx.x;
    const int lane = tid & 63;
    const int gw   = (blockIdx.x * 256 + tid) >> 6;
    const int kc   = gw % 96;
    const int row  = (gw / 96) * 64 + lane;
    const float4 a = *reinterpret_cast<const float4*>(in + (size_t)row * 768 + kc * 8);
    const float4 b = *reinterpret_cast<const float4*>(in + (size_t)row * 768 + kc * 8 + 4);
    f16x8 h;
    h[0] = (_Float16)a.x; h[1] = (_Float16)a.y; h[2] = (_Float16)a.z; h[3] = (_Float16)a.w;
    h[4] = (_Float16)b.x; h[5] = (_Float16)b.y; h[6] = (_Float16)b.z; h[7] = (_Float16)b.w;
    *reinterpret_cast<f16x8*>(
        out + (size_t)(row >> 7) * PSTRIDE + (size_t)kc * 1024 + (row & 127) * 8) = h;
}

// ---------------------------------------------------------------------------
// fp16 MFMA GEMM on TILED inputs. BM=BN=128, BK=64, 4 waves, 64x64/wave.
// ---------------------------------------------------------------------------
template <bool SCATTER>
__global__ __launch_bounds__(256)
void gemm_mfma(const _Float16* __restrict__ At, const _Float16* __restrict__ Bt,
               _Float16* __restrict__ qb, _Float16* __restrict__ kpd,
               _Float16* __restrict__ vtb, float* __restrict__ C,
               int N, int nx)
{
    __shared__ _Float16 As[8 * 128 * 8];
    __shared__ _Float16 Bs[8 * 128 * 8];

    const int tid  = threadIdx.x;
    const int lane = tid & 63;
    const int wid  = tid >> 6;
    const int li   = lane & 15;
    const int lg   = lane >> 4;
    const int wr   = wid >> 1;
    const int wc   = wid & 1;

    const int qch = gridDim.x >> 3;
    const int id  = (blockIdx.x & 7) * qch + (blockIdx.x >> 3);
    const int m0  = (id / nx) * 128;
    const int n0  = (id % nx) * 128;

    const _Float16* baseA = At + (size_t)(m0 >> 7) * PSTRIDE;
    const _Float16* baseB = Bt + (size_t)(n0 >> 7) * PSTRIDE;

    f32x4 acc[4][4];
#pragma unroll
    for (int i = 0; i < 4; ++i)
#pragma unroll
        for (int j = 0; j < 4; ++j) acc[i][j] = (f32x4)0.f;

    for (int k0 = 0; k0 < Dm; k0 += 64) {
        const _Float16* pa = baseA + (k0 >> 3) * 1024;
        const _Float16* pb = baseB + (k0 >> 3) * 1024;
#pragma unroll
        for (int i = 0; i < 4; ++i) {
            const int s = wid * 64 + i * 256;        // wave-uniform slot base
            __builtin_amdgcn_global_load_lds(
                (const __attribute__((address_space(1))) void*)(pa + (size_t)(s + lane) * 8),
                (__attribute__((address_space(3))) void*)&As[s * 8], 16, 0, 0);
            __builtin_amdgcn_global_load_lds(
                (const __attribute__((address_space(1))) void*)(pb + (size_t)(s + lane) * 8),
                (__attribute__((address_space(3))) void*)&Bs[s * 8], 16, 0, 0);
        }
        __syncthreads();

#pragma unroll
        for (int c = 0; c < 2; ++c) {
            f16x8 af[4], bf[4];
#pragma unroll
            for (int i = 0; i < 4; ++i)
                af[i] = *reinterpret_cast<const f16x8*>(
                    &As[((c * 4 + lg) * 128 + wr * 64 + i * 16 + li) * 8]);
#pragma unroll
            for (int j = 0; j < 4; ++j)
                bf[j] = *reinterpret_cast<const f16x8*>(
                    &Bs[((c * 4 + lg) * 128 + wc * 64 + j * 16 + li) * 8]);
#pragma unroll
            for (int i = 0; i < 4; ++i)
#pragma unroll
                for (int j = 0; j < 4; ++j)
                    acc[i][j] = __builtin_amdgcn_mfma_f32_16x16x32_f16(
                        af[i], bf[j], acc[i][j], 0, 0, 0);
        }
        __syncthreads();
    }

#pragma unroll
    for (int i = 0; i < 4; ++i) {
#pragma unroll
        for (int r = 0; r < 4; ++r) {
            const int m = m0 + wr * 64 + i * 16 + lg * 4 + r;
            if (SCATTER) {
                const int b_ = m >> 11, t_ = m & 2047;
#pragma unroll
                for (int j = 0; j < 4; ++j) {
                    const int e = n0 + wc * 64 + j * 16 + li;
                    const int c = e / Dm;
                    const int rem = e - c * Dm;
                    const int h = rem / HD;
                    const int d = rem - h * HD;
                    const size_t bhx = (size_t)(b_ * H + h);
                    const float v = acc[i][j][r];
                    if (c == 0)
                        qb[(bhx * T + t_) * HD + d] = (_Float16)(v * QS);
                    else if (c == 1)
                        kpd[(bhx * T + t_) * 128 + d] = (_Float16)v;
                    else
                        vtb[(bhx * 96 + d) * T + t_] = (_Float16)v;
                }
            } else {
#pragma unroll
                for (int j = 0; j < 4; ++j) {
                    const int n = n0 + wc * 64 + j * 16 + li;
                    C[(size_t)m * N + n] = acc[i][j][r];
                }
            }
        }
    }
}

// ---------------------------------------------------------------------------
// MFMA flash attention, causal, fp16 in/out. Fixed-max softmax (M0 folded
// into QK^T C-init), l via ones-column in V (7th dt MFMA). Block = 4 waves
// x 16 q rows; KV tiles of 64, double-buffered counted-vmcnt prefetch.
// ---------------------------------------------------------------------------
__global__ __launch_bounds__(256)
void attn_mfma(const _Float16* __restrict__ QG, const _Float16* __restrict__ KG,
               const _Float16* __restrict__ VtG, _Float16* __restrict__ aoh)
{
    __shared__ __align__(16) _Float16 Klds[2][64 * 128];
    __shared__ __align__(16) _Float16 Vlds[2][112 * 64];  // rows 96..111: ones/zeros pad
    __shared__ __align__(16) _Float16 Pl[4][16][96];

    const int tid  = threadIdx.x;
    const int lane = tid & 63;
    const int wid  = tid >> 6;
    const int lg   = lane >> 4;
    const int li   = lane & 15;

    const int bh = blockIdx.x & 31;
    const int u  = blockIdx.x >> 5;              // 0..31
    const int qt_blk = (u & 1) ? (u >> 1) : (31 - (u >> 1));  // balanced pairs
    const int q0     = qt_blk * 64;
    const int q0w    = q0 + wid * 16;
    const int ntiles = qt_blk + 1;

    // ones row (96) + zero rows (97..111) in both V buffers
    {
        const u32 one2 = 0x3C003C00u;
        u32* vp0 = reinterpret_cast<u32*>(&Vlds[0][96 * 64]);
        u32* vp1 = reinterpret_cast<u32*>(&Vlds[1][96 * 64]);
#pragma unroll
        for (int i = tid; i < 512; i += 256) {
            const u32 v = (i < 32) ? one2 : 0u;
            vp0[i] = v; vp1[i] = v;
        }
    }
    __syncthreads();

    // Q fragments straight to registers (B-frag: col=li -> q row, k=d)
    f16x8 qf[3];
    {
        const _Float16* qrow = QG + ((size_t)bh * T + q0w + li) * HD;
#pragma unroll
        for (int ch = 0; ch < 3; ++ch)
            qf[ch] = *reinterpret_cast<const f16x8*>(qrow + ch * 32 + lg * 8);
    }

    const int rK = lane >> 4;                  // 0..3
    const int cK = (lane & 15) * 8;
    const int rV = lane >> 3;                  // 0..7
    const int cV = (lane & 7) * 8;
    auto STAGE = [&](int kb, int b) {
#pragma unroll
        for (int ii = 0; ii < 4; ++ii) {
            const int r  = wid * 16 + ii * 4 + rK;
            const int c0 = cK ^ (((ii * 4 + rK) & 7) << 3);
            const _Float16* src = KG + ((size_t)(bh * T + kb + r)) * 128 + c0;
            __builtin_amdgcn_global_load_lds(
                (const __attribute__((address_space(1))) void*)src,
                (__attribute__((address_space(3))) void*)&Klds[b][(wid * 16 + ii * 4) * 128],
                16, 0, 0);
        }
#pragma unroll
        for (int jj = 0; jj < 3; ++jj) {
            const int r  = wid * 24 + jj * 8 + rV;
            const int c0 = cV ^ (rV << 3);
            const _Float16* src = VtG + ((size_t)(bh * 96 + r)) * T + kb + c0;
            __builtin_amdgcn_global_load_lds(
                (const __attribute__((address_space(1))) void*)src,
                (__attribute__((address_space(3))) void*)&Vlds[b][(wid * 24 + jj * 8) * 64],
                16, 0, 0);
        }
    };

    f32x4 acc[7];
#pragma unroll
    for (int dt = 0; dt < 7; ++dt) acc[dt] = (f32x4)0.f;

    STAGE(0, 0);
    int p = 0;
    for (int t = 0; t < ntiles; ++t) {
        const int kb = t * KVB;
        const bool has_next = (t + 1 < ntiles);
        if (has_next) {
            STAGE(kb + KVB, p ^ 1);
            asm volatile("s_waitcnt vmcnt(7)" ::: "memory");   // buf[p] done
        } else {
            asm volatile("s_waitcnt vmcnt(0)" ::: "memory");
        }
        __builtin_amdgcn_s_barrier();

        const int nkt = min(4, ((q0w + 15 - kb) >> 4) + 1);

        // K A-frags (row=li -> k row, k=d), swizzled read
        f16x8 kf[4][3];
#pragma unroll
        for (int kt = 0; kt < 4; ++kt)
            if (kt < nkt) {
#pragma unroll
                for (int ch = 0; ch < 3; ++ch) {
                    const int row = kt * 16 + li;
                    const int cs  = (ch * 32 + lg * 8) ^ ((row & 7) << 3);
                    kf[kt][ch] = *reinterpret_cast<const f16x8*>(
                        &Klds[p][row * 128 + cs]);
                }
            }

        // S^T - M0 = K @ Q + (-M0)   (C-init carries the fixed max)
        f32x4 st[4];
#pragma unroll
        for (int kt = 0; kt < 4; ++kt) {
            st[kt] = (f32x4)(-M0);
            if (kt < nkt) {
#pragma unroll
                for (int ch = 0; ch < 3; ++ch)
                    st[kt] = __builtin_amdgcn_mfma_f32_16x16x32_f16(
                        kf[kt][ch], qf[ch], st[kt], 0, 0, 0);
            }
        }

        // causal mask on diagonal sub-tiles only
        const int qg = q0w + li;
#pragma unroll
        for (int kt = 0; kt < 4; ++kt)
            if (kt < nkt && kb + kt * 16 + 15 > q0w) {
#pragma unroll
                for (int rr = 0; rr < 4; ++rr) {
                    const int kg = kb + kt * 16 + lg * 4 + rr;
                    if (kg > qg) st[kt][rr] = -1e30f;
                }
            }

        // p = exp2(st), pack f16, stage to Pl (4-way-max bank pattern)
#pragma unroll
        for (int kt = 0; kt < 4; ++kt)
            if (kt < nkt) {
                const auto a = __builtin_amdgcn_cvt_pkrtz(
                    __builtin_amdgcn_exp2f(st[kt][0]),
                    __builtin_amdgcn_exp2f(st[kt][1]));
                const auto b = __builtin_amdgcn_cvt_pkrtz(
                    __builtin_amdgcn_exp2f(st[kt][2]),
                    __builtin_amdgcn_exp2f(st[kt][3]));
                const u64 w = (u64)__builtin_bit_cast(u32, a) |
                              ((u64)__builtin_bit_cast(u32, b) << 32);
                *reinterpret_cast<u64*>(&Pl[wid][li][kt * 16 + lg * 4]) = w;
            }
        if (nkt & 1)
            *reinterpret_cast<u64*>(&Pl[wid][li][nkt * 16 + lg * 4]) = 0ull;

        // PV (+ ones-column row-sum in dt=6): A=P frag, B=V frag
        const int npc = (nkt + 1) >> 1;
#pragma unroll
        for (int pc = 0; pc < 2; ++pc)
            if (pc < npc) {
                const f16x8 pf = *reinterpret_cast<const f16x8*>(
                    &Pl[wid][li][pc * 32 + lg * 8]);
#pragma unroll
                for (int dt = 0; dt < 7; ++dt) {
                    const int row = dt * 16 + li;
                    const int cs  = (pc * 32 + lg * 8) ^ ((row & 7) << 3);
                    const f16x8 vf = *reinterpret_cast<const f16x8*>(
                        &Vlds[p][row * 64 + cs]);
                    acc[dt] = __builtin_amdgcn_mfma_f32_16x16x32_f16(
                        pf, vf, acc[dt], 0, 0, 0);
                }
            }

        asm volatile("s_waitcnt lgkmcnt(0)" ::: "memory");
        __builtin_amdgcn_s_barrier();   // all reads of buf[p] done
        p ^= 1;
    }

    // epilogue: l = acc[6] at li==0 lanes; normalize; tiled fp16 store
    const int ob = bh >> 3, oh = bh & 7;
#pragma unroll
    for (int rr = 0; rr < 4; ++rr) {
        const float l    = __shfl(acc[6][rr], lg << 4);
        const float linv = 1.0f / l;
        const int m = ob * T + q0w + lg * 4 + rr;
        _Float16* op = aoh + (size_t)(m >> 7) * PSTRIDE + (size_t)(m & 127) * 8
                     + (size_t)(oh * 12 + (li >> 3)) * 1024 + (li & 7);
#pragma unroll
        for (int dt = 0; dt < 6; ++dt)
            op[dt * 2048] = (_Float16)(acc[dt][rr] * linv);
    }
}

// ---------------------------------------------------------------------------
extern "C" void kernel_launch(void* const* d_in, const int* in_sizes, int n_in,
                              void* d_out, int out_size, void* d_ws, size_t ws_size,
                              hipStream_t stream)
{
    const float* x     = (const float*)d_in[0];
    const float* w_qkv = (const float*)d_in[1];
    const float* w_out = (const float*)d_in[2];
    // d_in[3] = leech kernel: orthogonal -> cancels in q.kT, ignored.

    _Float16* qb  = (_Float16*)d_ws;                 // [BH][T][96]
    _Float16* kpd = qb + QEL;                        // [BH][T][128]
    _Float16* vtb = kpd + KEL;                       // [BH][96][T]
    _Float16* aoh = vtb + QEL;                       // tiled [64][96][128][8]
    _Float16* xh  = aoh + (size_t)Bq * T * Dm;       // tiled [64][96][128][8]
    _Float16* wqh = xh + (size_t)Bq * T * Dm;        // tiled [18][96][128][8]
    _Float16* woh = wqh + (size_t)3 * Dm * Dm;       // tiled [6][96][128][8]
    float* out = (float*)d_out;

    const int M = Bq * T;  // 8192

    cvt_tile<<<dim3(M * 96 / 256), dim3(256), 0, stream>>>(x, xh);
    cvt_tile<<<dim3(3 * Dm * 96 / 256), dim3(256), 0, stream>>>(w_qkv, wqh);
    cvt_tile<<<dim3(Dm * 96 / 256), dim3(256), 0, stream>>>(w_out, woh);

    gemm_mfma<true><<<dim3((3 * Dm / 128) * (M / 128)), dim3(256), 0, stream>>>(
        xh, wqh, qb, kpd, vtb, nullptr, 3 * Dm, 3 * Dm / 128);

    attn_mfma<<<dim3(BH * (T / 64)), dim3(256), 0, stream>>>(qb, kpd, vtb, aoh);

    gemm_mfma<false><<<dim3((Dm / 128) * (M / 128)), dim3(256), 0, stream>>>(
        aoh, woh, nullptr, nullptr, nullptr, out, Dm, Dm / 128);
}

// Round 11
// 180.355 us; speedup vs baseline: 1.0317x; 1.0317x over previous
//
#include <hip/hip_runtime.h>
#include <cstdint>
#include <cstddef>

#define Bq 4
#define T 2048
#define Dm 768
#define H 8
#define HD 96
#define BH 32
#define QEL ((size_t)BH*T*HD)     // q / v^T element count
#define KEL ((size_t)BH*T*128)    // padded K element count
#define PSTRIDE 98304             // tiled panel stride = (768/8)*128*8 elems
// q pre-scaled by HD^-0.5 * log2(e): attention uses exp2 directly
#define QS 0.14724703336f
#define KVB 64
#define M0 12.0f                  // fixed softmax max (log2 domain)

typedef unsigned int u32;
typedef unsigned long long u64;
typedef _Float16 f16x8 __attribute__((ext_vector_type(8)));
typedef _Float16 f16x4 __attribute__((ext_vector_type(4)));
typedef float f32x4 __attribute__((ext_vector_type(4)));

// ---------------------------------------------------------------------------
// f32 [R][768] row-major -> fp16 tiled [R/128][96][128][8].
// ---------------------------------------------------------------------------
__global__ __launch_bounds__(256)
void cvt_tile(const float* __restrict__ in, _Float16* __restrict__ out)
{
    const int tid  = threadIdx.x;
    const int lane = tid & 63;
    const int gw   = (blockIdx.x * 256 + tid) >> 6;
    const int kc   = gw % 96;
    const int row  = (gw / 96) * 64 + lane;
    const float4 a = *reinterpret_cast<const float4*>(in + (size_t)row * 768 + kc * 8);
    const float4 b = *reinterpret_cast<const float4*>(in + (size_t)row * 768 + kc * 8 + 4);
    f16x8 h;
    h[0] = (_Float16)a.x; h[1] = (_Float16)a.y; h[2] = (_Float16)a.z; h[3] = (_Float16)a.w;
    h[4] = (_Float16)b.x; h[5] = (_Float16)b.y; h[6] = (_Float16)b.z; h[7] = (_Float16)b.w;
    *reinterpret_cast<f16x8*>(
        out + (size_t)(row >> 7) * PSTRIDE + (size_t)kc * 1024 + (row & 127) * 8) = h;
}

// ---------------------------------------------------------------------------
// fp16 MFMA GEMM on TILED inputs. BM=BN=128, BK=64, 4 waves, 64x64/wave.
// ---------------------------------------------------------------------------
template <bool SCATTER>
__global__ __launch_bounds__(256)
void gemm_mfma(const _Float16* __restrict__ At, const _Float16* __restrict__ Bt,
               _Float16* __restrict__ qb, _Float16* __restrict__ kpd,
               _Float16* __restrict__ vtb, float* __restrict__ C,
               int N, int nx)
{
    __shared__ _Float16 As[8 * 128 * 8];
    __shared__ _Float16 Bs[8 * 128 * 8];

    const int tid  = threadIdx.x;
    const int lane = tid & 63;
    const int wid  = tid >> 6;
    const int li   = lane & 15;
    const int lg   = lane >> 4;
    const int wr   = wid >> 1;
    const int wc   = wid & 1;

    const int qch = gridDim.x >> 3;
    const int id  = (blockIdx.x & 7) * qch + (blockIdx.x >> 3);
    const int m0  = (id / nx) * 128;
    const int n0  = (id % nx) * 128;

    const _Float16* baseA = At + (size_t)(m0 >> 7) * PSTRIDE;
    const _Float16* baseB = Bt + (size_t)(n0 >> 7) * PSTRIDE;

    f32x4 acc[4][4];
#pragma unroll
    for (int i = 0; i < 4; ++i)
#pragma unroll
        for (int j = 0; j < 4; ++j) acc[i][j] = (f32x4)0.f;

    for (int k0 = 0; k0 < Dm; k0 += 64) {
        const _Float16* pa = baseA + (k0 >> 3) * 1024;
        const _Float16* pb = baseB + (k0 >> 3) * 1024;
#pragma unroll
        for (int i = 0; i < 4; ++i) {
            const int s = wid * 64 + i * 256;        // wave-uniform slot base
            __builtin_amdgcn_global_load_lds(
                (const __attribute__((address_space(1))) void*)(pa + (size_t)(s + lane) * 8),
                (__attribute__((address_space(3))) void*)&As[s * 8], 16, 0, 0);
            __builtin_amdgcn_global_load_lds(
                (const __attribute__((address_space(1))) void*)(pb + (size_t)(s + lane) * 8),
                (__attribute__((address_space(3))) void*)&Bs[s * 8], 16, 0, 0);
        }
        __syncthreads();

#pragma unroll
        for (int c = 0; c < 2; ++c) {
            f16x8 af[4], bf[4];
#pragma unroll
            for (int i = 0; i < 4; ++i)
                af[i] = *reinterpret_cast<const f16x8*>(
                    &As[((c * 4 + lg) * 128 + wr * 64 + i * 16 + li) * 8]);
#pragma unroll
            for (int j = 0; j < 4; ++j)
                bf[j] = *reinterpret_cast<const f16x8*>(
                    &Bs[((c * 4 + lg) * 128 + wc * 64 + j * 16 + li) * 8]);
#pragma unroll
            for (int i = 0; i < 4; ++i)
#pragma unroll
                for (int j = 0; j < 4; ++j)
                    acc[i][j] = __builtin_amdgcn_mfma_f32_16x16x32_f16(
                        af[i], bf[j], acc[i][j], 0, 0, 0);
        }
        __syncthreads();
    }

#pragma unroll
    for (int i = 0; i < 4; ++i) {
#pragma unroll
        for (int r = 0; r < 4; ++r) {
            const int m = m0 + wr * 64 + i * 16 + lg * 4 + r;
            if (SCATTER) {
                const int b_ = m >> 11, t_ = m & 2047;
#pragma unroll
                for (int j = 0; j < 4; ++j) {
                    const int e = n0 + wc * 64 + j * 16 + li;
                    const int c = e / Dm;
                    const int rem = e - c * Dm;
                    const int h = rem / HD;
                    const int d = rem - h * HD;
                    const size_t bhx = (size_t)(b_ * H + h);
                    const float v = acc[i][j][r];
                    if (c == 0)
                        qb[(bhx * T + t_) * HD + d] = (_Float16)(v * QS);
                    else if (c == 1)
                        kpd[(bhx * T + t_) * 128 + d] = (_Float16)v;
                    else
                        vtb[(bhx * 96 + d) * T + t_] = (_Float16)v;
                }
            } else {
#pragma unroll
                for (int j = 0; j < 4; ++j) {
                    const int n = n0 + wc * 64 + j * 16 + li;
                    C[(size_t)m * N + n] = acc[i][j][r];
                }
            }
        }
    }
}

// ---------------------------------------------------------------------------
// MFMA flash attention, causal, fp16 in/out. Fixed-max softmax (M0 in C-init),
// l via ones-column in V (7th dt MFMA). Block = 4 waves x 32 q rows
// (QBLK=128, 2 sub-tiles of 16 per wave); KV tiles of 64, double-buffered
// counted-vmcnt prefetch. V-frags shared across the two q sub-tiles.
// ---------------------------------------------------------------------------
__global__ __launch_bounds__(256)
void attn_mfma(const _Float16* __restrict__ QG, const _Float16* __restrict__ KG,
               const _Float16* __restrict__ VtG, _Float16* __restrict__ aoh)
{
    __shared__ __align__(16) _Float16 Klds[2][64 * 128];
    __shared__ __align__(16) _Float16 Vlds[2][112 * 64];  // rows 96..111: ones/zeros
    __shared__ __align__(16) _Float16 Pl[4][32][72];

    const int tid  = threadIdx.x;
    const int lane = tid & 63;
    const int wid  = tid >> 6;
    const int lg   = lane >> 4;
    const int li   = lane & 15;

    const int bh = blockIdx.x & 31;
    const int u  = blockIdx.x >> 5;              // 0..15
    const int qt_blk = (u & 1) ? (u >> 1) : (15 - (u >> 1));  // balanced pairs
    const int q0     = qt_blk * 128;
    const int ntiles = 2 * qt_blk + 2;

    // ones row (96) + zero rows (97..111) in both V buffers
    {
        const u32 one2 = 0x3C003C00u;
        u32* vp0 = reinterpret_cast<u32*>(&Vlds[0][96 * 64]);
        u32* vp1 = reinterpret_cast<u32*>(&Vlds[1][96 * 64]);
#pragma unroll
        for (int i = tid; i < 512; i += 256) {
            const u32 v = (i < 32) ? one2 : 0u;
            vp0[i] = v; vp1[i] = v;
        }
    }
    __syncthreads();

    // Q fragments straight to registers, 2 sub-tiles per wave
    f16x8 qf[2][3];
#pragma unroll
    for (int qt = 0; qt < 2; ++qt) {
        const _Float16* qrow = QG + ((size_t)bh * T + q0 + wid * 32 + qt * 16 + li) * HD;
#pragma unroll
        for (int ch = 0; ch < 3; ++ch)
            qf[qt][ch] = *reinterpret_cast<const f16x8*>(qrow + ch * 32 + lg * 8);
    }

    const int rK = lane >> 4;                  // 0..3
    const int cK = (lane & 15) * 8;
    const int rV = lane >> 3;                  // 0..7
    const int cV = (lane & 7) * 8;
    auto STAGE = [&](int kb, int b) {
#pragma unroll
        for (int ii = 0; ii < 4; ++ii) {
            const int r  = wid * 16 + ii * 4 + rK;
            const int c0 = cK ^ (((ii * 4 + rK) & 7) << 3);
            const _Float16* src = KG + ((size_t)(bh * T + kb + r)) * 128 + c0;
            __builtin_amdgcn_global_load_lds(
                (const __attribute__((address_space(1))) void*)src,
                (__attribute__((address_space(3))) void*)&Klds[b][(wid * 16 + ii * 4) * 128],
                16, 0, 0);
        }
#pragma unroll
        for (int jj = 0; jj < 3; ++jj) {
            const int r  = wid * 24 + jj * 8 + rV;
            const int c0 = cV ^ (rV << 3);
            const _Float16* src = VtG + ((size_t)(bh * 96 + r)) * T + kb + c0;
            __builtin_amdgcn_global_load_lds(
                (const __attribute__((address_space(1))) void*)src,
                (__attribute__((address_space(3))) void*)&Vlds[b][(wid * 24 + jj * 8) * 64],
                16, 0, 0);
        }
    };

    f32x4 acc[2][7];
#pragma unroll
    for (int qt = 0; qt < 2; ++qt)
#pragma unroll
        for (int dt = 0; dt < 7; ++dt) acc[qt][dt] = (f32x4)0.f;

    STAGE(0, 0);
    int p = 0;
    for (int t = 0; t < ntiles; ++t) {
        const int kb = t * KVB;
        const bool has_next = (t + 1 < ntiles);
        if (has_next) {
            STAGE(kb + KVB, p ^ 1);
            asm volatile("s_waitcnt vmcnt(7)" ::: "memory");   // buf[p] done
        } else {
            asm volatile("s_waitcnt vmcnt(0)" ::: "memory");
        }
        __builtin_amdgcn_s_barrier();

        // per-sub-tile causal bounds (qt=1 is the wider one)
        const int qw0  = q0 + wid * 32;
        int nkt[2];
#pragma unroll
        for (int qt = 0; qt < 2; ++qt)
            nkt[qt] = min(4, max(0, ((qw0 + qt * 16 + 15 - kb) >> 4) + 1));
        const int nktmax = nkt[1];

        // K A-frags (shared across sub-tiles), swizzled read
        f16x8 kf[4][3];
#pragma unroll
        for (int kt = 0; kt < 4; ++kt)
            if (kt < nktmax) {
#pragma unroll
                for (int ch = 0; ch < 3; ++ch) {
                    const int row = kt * 16 + li;
                    const int cs  = (ch * 32 + lg * 8) ^ ((row & 7) << 3);
                    kf[kt][ch] = *reinterpret_cast<const f16x8*>(
                        &Klds[p][row * 128 + cs]);
                }
            }

#pragma unroll
        for (int qt = 0; qt < 2; ++qt) {
            if (nkt[qt] <= 0) continue;
            const int q0w = qw0 + qt * 16;

            // S^T - M0 = K @ Q + (-M0)
            f32x4 st[4];
#pragma unroll
            for (int kt = 0; kt < 4; ++kt) {
                st[kt] = (f32x4)(-M0);
                if (kt < nkt[qt]) {
#pragma unroll
                    for (int ch = 0; ch < 3; ++ch)
                        st[kt] = __builtin_amdgcn_mfma_f32_16x16x32_f16(
                            kf[kt][ch], qf[qt][ch], st[kt], 0, 0, 0);
                }
            }

            // causal mask on diagonal sub-tiles only
            const int qg = q0w + li;
#pragma unroll
            for (int kt = 0; kt < 4; ++kt)
                if (kt < nkt[qt] && kb + kt * 16 + 15 > q0w) {
#pragma unroll
                    for (int rr = 0; rr < 4; ++rr) {
                        const int kg = kb + kt * 16 + lg * 4 + rr;
                        if (kg > qg) st[kt][rr] = -1e30f;
                    }
                }

            // p = exp2(st), pack f16, stage to Pl
#pragma unroll
            for (int kt = 0; kt < 4; ++kt)
                if (kt < nkt[qt]) {
                    const auto a = __builtin_amdgcn_cvt_pkrtz(
                        __builtin_amdgcn_exp2f(st[kt][0]),
                        __builtin_amdgcn_exp2f(st[kt][1]));
                    const auto b = __builtin_amdgcn_cvt_pkrtz(
                        __builtin_amdgcn_exp2f(st[kt][2]),
                        __builtin_amdgcn_exp2f(st[kt][3]));
                    const u64 w = (u64)__builtin_bit_cast(u32, a) |
                                  ((u64)__builtin_bit_cast(u32, b) << 32);
                    *reinterpret_cast<u64*>(&Pl[wid][qt * 16 + li][kt * 16 + lg * 4]) = w;
                }
            if (nkt[qt] & 1)
                *reinterpret_cast<u64*>(&Pl[wid][qt * 16 + li][nkt[qt] * 16 + lg * 4]) = 0ull;
        }

        // PV (+ ones-column row-sum in dt=6): V frags shared across sub-tiles
        const int npc0 = (nkt[0] + 1) >> 1;
        const int npc1 = (nkt[1] + 1) >> 1;
#pragma unroll
        for (int pc = 0; pc < 2; ++pc) {
            if (pc >= npc1) continue;    // npc1 >= npc0
            const f16x8 pf1 = *reinterpret_cast<const f16x8*>(
                &Pl[wid][16 + li][pc * 32 + lg * 8]);
            f16x8 pf0;
            const bool do0 = (pc < npc0);
            if (do0)
                pf0 = *reinterpret_cast<const f16x8*>(
                    &Pl[wid][li][pc * 32 + lg * 8]);
#pragma unroll
            for (int dt = 0; dt < 7; ++dt) {
                const int row = dt * 16 + li;
                const int cs  = (pc * 32 + lg * 8) ^ ((row & 7) << 3);
                const f16x8 vf = *reinterpret_cast<const f16x8*>(
                    &Vlds[p][row * 64 + cs]);
                acc[1][dt] = __builtin_amdgcn_mfma_f32_16x16x32_f16(
                    pf1, vf, acc[1][dt], 0, 0, 0);
                if (do0)
                    acc[0][dt] = __builtin_amdgcn_mfma_f32_16x16x32_f16(
                        pf0, vf, acc[0][dt], 0, 0, 0);
            }
        }

        asm volatile("s_waitcnt lgkmcnt(0)" ::: "memory");
        __builtin_amdgcn_s_barrier();   // all reads of buf[p] done
        p ^= 1;
    }

    // epilogue: l = acc[qt][6] at li==0 lanes; normalize; tiled fp16 store
    const int ob = bh >> 3, oh = bh & 7;
#pragma unroll
    for (int qt = 0; qt < 2; ++qt)
#pragma unroll
        for (int rr = 0; rr < 4; ++rr) {
            const float l    = __shfl(acc[qt][6][rr], lg << 4);
            const float linv = 1.0f / l;
            const int m = ob * T + q0 + wid * 32 + qt * 16 + lg * 4 + rr;
            _Float16* op = aoh + (size_t)(m >> 7) * PSTRIDE + (size_t)(m & 127) * 8
                         + (size_t)(oh * 12 + (li >> 3)) * 1024 + (li & 7);
#pragma unroll
            for (int dt = 0; dt < 6; ++dt)
                op[dt * 2048] = (_Float16)(acc[qt][dt][rr] * linv);
        }
}

// ---------------------------------------------------------------------------
extern "C" void kernel_launch(void* const* d_in, const int* in_sizes, int n_in,
                              void* d_out, int out_size, void* d_ws, size_t ws_size,
                              hipStream_t stream)
{
    const float* x     = (const float*)d_in[0];
    const float* w_qkv = (const float*)d_in[1];
    const float* w_out = (const float*)d_in[2];
    // d_in[3] = leech kernel: orthogonal -> cancels in q.kT, ignored.

    _Float16* qb  = (_Float16*)d_ws;                 // [BH][T][96]
    _Float16* kpd = qb + QEL;                        // [BH][T][128]
    _Float16* vtb = kpd + KEL;                       // [BH][96][T]
    _Float16* aoh = vtb + QEL;                       // tiled [64][96][128][8]
    _Float16* xh  = aoh + (size_t)Bq * T * Dm;       // tiled [64][96][128][8]
    _Float16* wqh = xh + (size_t)Bq * T * Dm;        // tiled [18][96][128][8]
    _Float16* woh = wqh + (size_t)3 * Dm * Dm;       // tiled [6][96][128][8]
    float* out = (float*)d_out;

    const int M = Bq * T;  // 8192

    cvt_tile<<<dim3(M * 96 / 256), dim3(256), 0, stream>>>(x, xh);
    cvt_tile<<<dim3(3 * Dm * 96 / 256), dim3(256), 0, stream>>>(w_qkv, wqh);
    cvt_tile<<<dim3(Dm * 96 / 256), dim3(256), 0, stream>>>(w_out, woh);

    gemm_mfma<true><<<dim3((3 * Dm / 128) * (M / 128)), dim3(256), 0, stream>>>(
        xh, wqh, qb, kpd, vtb, nullptr, 3 * Dm, 3 * Dm / 128);

    attn_mfma<<<dim3(BH * (T / 128)), dim3(256), 0, stream>>>(qb, kpd, vtb, aoh);

    gemm_mfma<false><<<dim3((Dm / 128) * (M / 128)), dim3(256), 0, stream>>>(
        aoh, woh, nullptr, nullptr, nullptr, out, Dm, Dm / 128);
}